// Round 14
// baseline (331.786 us; speedup 1.0000x reference)
//
#include <hip/hip_runtime.h>
#include <hip/hip_bf16.h>

#define DFEAT 256
#define RSTRIDE 64

typedef __attribute__((ext_vector_type(8))) short bf16x8;
typedef __attribute__((ext_vector_type(4))) float f32x4;

__device__ __forceinline__ float bf2f(unsigned short u) {
  return __builtin_bit_cast(float, ((unsigned)u) << 16);
}
__device__ __forceinline__ unsigned short f2bf(float f) {
  __hip_bfloat16 h = __float2bfloat16(f);  // RTNE
  return *reinterpret_cast<unsigned short*>(&h);
}
__device__ __forceinline__ void gload_lds16(const void* g, void* l) {
  __builtin_amdgcn_global_load_lds(
      (const __attribute__((address_space(1))) void*)g,
      (__attribute__((address_space(3))) void*)l, 16, 0, 0);
}

// ---------------- padded-CSR build: one pass over edges ----------------

__global__ void k_build(const int* __restrict__ ei0, const int* __restrict__ ei1, int E,
                        int* __restrict__ cnt, int* __restrict__ colsP) {
  int i = blockIdx.x * blockDim.x + threadIdx.x;
  if (i >= E) return;
  int r = ei0[i];
  int pos = atomicAdd(&cnt[r], 1);
  if (pos < RSTRIDE) colsP[(size_t)r * RSTRIDE + pos] = ei1[i];
}

// ---------------- fused converts: weight-combine + dis + x->bf16 ----------------
// Blocks [0,256): combined weights for the pure-L chain:
//   out = x(W0-W2) + S1(W1-3W3) + S2(2W2) + S3(4W3) + b,  S_k = L^k x
// Blocks [256,256+nb): dis = rsqrt(deg+1). Blocks [256+nb,...): x f32->bf16.

__global__ __launch_bounds__(256) void k_f2bfwt(const float* __restrict__ x,
                                                unsigned short* __restrict__ xbf, int n4,
                                                const float* __restrict__ W,
                                                unsigned short* __restrict__ WT,
                                                const int* __restrict__ cnt,
                                                float* __restrict__ dis, int N, int nb) {
  int b = blockIdx.x;
  if (b < 256) {
    int idx = b * 256 + threadIdx.x;  // (k,n) over 65536
    int n = idx & 255;
    int k = idx >> 8;
    float w0 = W[idx];
    float w1 = W[65536 + idx];
    float w2 = W[2 * 65536 + idx];
    float w3 = W[3 * 65536 + idx];
    int t = (n << 8) | k;  // transposed (n,k)
    WT[t]             = f2bf(w0 - w2);
    WT[65536 + t]     = f2bf(w1 - 3.0f * w3);
    WT[2 * 65536 + t] = f2bf(2.0f * w2);
    WT[3 * 65536 + t] = f2bf(4.0f * w3);
    return;
  }
  if (b < 256 + nb) {
    int i = (b - 256) * 256 + threadIdx.x;
    if (i < N) dis[i] = rsqrtf((float)(cnt[i] + 1));  // deg incl. appended self loop
    return;
  }
  int i = (b - 256 - nb) * 256 + threadIdx.x;
  if (i >= n4) return;
  float4 f = *(const float4*)(x + (size_t)i * 4);
  ushort4 u;
  u.x = f2bf(f.x); u.y = f2bf(f.y); u.z = f2bf(f.z); u.w = f2bf(f.w);
  *(ushort4*)(xbf + (size_t)i * 4) = u;
}

// ---------------- SpMM (bf16): y = L v  (pure Laplacian apply) ----------------
// One wave per row; lane owns 4 contiguous feats. Unroll x4 with early exit
// (4 independent gather chains). No LDS, no shfl, no barrier. R8-validated.

__global__ __launch_bounds__(256) void k_spmm_bf(
    const unsigned short* __restrict__ v, unsigned short* __restrict__ y,
    const int* __restrict__ cnt, const int* __restrict__ colsP,
    const float* __restrict__ dis, int N) {
  int r = blockIdx.x * 4 + (threadIdx.x >> 6);
  if (r >= N) return;
  int lane = threadIdx.x & 63;
  int fo = lane * 4;
  int len = cnt[r];
  if (len > RSTRIDE) len = RSTRIDE;
  const int* cp = colsP + (size_t)r * RSTRIDE;
  float dr = dis[r];
  float a0 = 0.f, a1 = 0.f, a2 = 0.f, a3 = 0.f;

  int e = 0;
  for (; e + 3 < len; e += 4) {
    int c0 = cp[e], c1 = cp[e + 1], c2 = cp[e + 2], c3 = cp[e + 3];
    float l0 = -dr * dis[c0] + (c0 == r ? 1.f : 0.f);
    float l1 = -dr * dis[c1] + (c1 == r ? 1.f : 0.f);
    float l2 = -dr * dis[c2] + (c2 == r ? 1.f : 0.f);
    float l3 = -dr * dis[c3] + (c3 == r ? 1.f : 0.f);
    uint2 u0 = *(const uint2*)(v + (size_t)c0 * DFEAT + fo);
    uint2 u1 = *(const uint2*)(v + (size_t)c1 * DFEAT + fo);
    uint2 u2 = *(const uint2*)(v + (size_t)c2 * DFEAT + fo);
    uint2 u3 = *(const uint2*)(v + (size_t)c3 * DFEAT + fo);
    a0 += l0 * bf2f(u0.x & 0xffff) + l1 * bf2f(u1.x & 0xffff) +
          l2 * bf2f(u2.x & 0xffff) + l3 * bf2f(u3.x & 0xffff);
    a1 += l0 * bf2f(u0.x >> 16) + l1 * bf2f(u1.x >> 16) +
          l2 * bf2f(u2.x >> 16) + l3 * bf2f(u3.x >> 16);
    a2 += l0 * bf2f(u0.y & 0xffff) + l1 * bf2f(u1.y & 0xffff) +
          l2 * bf2f(u2.y & 0xffff) + l3 * bf2f(u3.y & 0xffff);
    a3 += l0 * bf2f(u0.y >> 16) + l1 * bf2f(u1.y >> 16) +
          l2 * bf2f(u2.y >> 16) + l3 * bf2f(u3.y >> 16);
  }
  for (; e < len; ++e) {
    int c = cp[e];
    float lv = -dr * dis[c] + (c == r ? 1.f : 0.f);
    uint2 u = *(const uint2*)(v + (size_t)c * DFEAT + fo);
    a0 += lv * bf2f(u.x & 0xffff);
    a1 += lv * bf2f(u.x >> 16);
    a2 += lv * bf2f(u.y & 0xffff);
    a3 += lv * bf2f(u.y >> 16);
  }

  float sc = 1.0f - dr * dr;  // appended self-loop
  uint2 uv = *(const uint2*)(v + (size_t)r * DFEAT + fo);
  a0 += sc * bf2f(uv.x & 0xffff);
  a1 += sc * bf2f(uv.x >> 16);
  a2 += sc * bf2f(uv.y & 0xffff);
  a3 += sc * bf2f(uv.y >> 16);

  uint2 o;
  o.x = (unsigned)f2bf(a0) | ((unsigned)f2bf(a1) << 16);
  o.y = (unsigned)f2bf(a2) | ((unsigned)f2bf(a3) << 16);
  *(uint2*)(y + (size_t)r * DFEAT + fo) = o;
}

// ---------------- fused MFMA GEMM: out = sum_g Ag @ Wg' + bias ----------------
// BM=64, BN=256 (A read exactly once). 4 waves, 64x64 tile each. BK=64.
// A staged in LDS (8 KB/tile, double-buffered = 16 KB; tiny barrier drain,
// 128B rows, XOR swizzle slot^=(row&7) -- 2-way aliasing only).
// B fragments loaded DIRECTLY from global per iteration: WT is 512 KB,
// L2/L1-hot (every block reads the same lines), no barrier involvement --
// each wave gets private latency-hiding work between barriers.

__global__ __launch_bounds__(256) void k_gemm4(
    const unsigned short* __restrict__ A0, const unsigned short* __restrict__ A1,
    const unsigned short* __restrict__ A2, const unsigned short* __restrict__ A3,
    const unsigned short* __restrict__ WT,  // [4][256][256] (g,n,k) combined
    const float* __restrict__ bias, float* __restrict__ C, int N) {
  __shared__ __align__(16) unsigned short As[2][64 * 64];  // 64 rows x 128B
  int tid = threadIdx.x;
  int lane = tid & 63;
  int w = tid >> 6;
  int brow = blockIdx.x * 64;

  f32x4 acc[4][4] = {};

  // B fragment base pointers: lane l covers column w*64 + j*16 + (l&15),
  // 16B of k at slot (l>>4)*8.
  const unsigned short* bbase[4];
#pragma unroll
  for (int j = 0; j < 4; ++j)
    bbase[j] = WT + (size_t)(w * 64 + j * 16 + (lane & 15)) * DFEAT + (lane >> 4) * 8;

  auto stageA = [&](int buf, int it) {
    int g = it >> 2;
    int k0 = (it & 3) * 64;
    const unsigned short* Asrc = g == 0 ? A0 : g == 1 ? A1 : g == 2 ? A2 : A3;
#pragma unroll
    for (int p = 0; p < 2; ++p) {
      int chunk = p * 256 + w * 64 + lane;  // 0..511 ; dest = base + lane*16
      int r = chunk >> 3;                   // 0..63
      int s = (chunk & 7) ^ (r & 7);        // pre-swizzled source slot
      int grow = brow + r;
      if (grow >= N) grow = N - 1;
      gload_lds16(Asrc + (size_t)grow * DFEAT + k0 + s * 8,
                  (char*)As[buf] + chunk * 16);
    }
  };

  stageA(0, 0);
  __syncthreads();  // tile 0 ready

  for (int it = 0; it < 16; ++it) {
    int cur = it & 1;
    if (it < 15) stageA(cur ^ 1, it + 1);  // next A-tile flies during compute
    int g = it >> 2;
    int k0 = (it & 3) * 64;
    size_t boff = (size_t)(g << 16) + k0;
#pragma unroll
    for (int ks = 0; ks < 2; ++ks) {
      bf16x8 af[4], bfr[4];
#pragma unroll
      for (int i = 0; i < 4; ++i) {
        int row = i * 16 + (lane & 15);
        int slot = (ks * 4 + (lane >> 4)) ^ (row & 7);
        af[i] = *(const bf16x8*)((const char*)As[cur] + row * 128 + slot * 16);
      }
#pragma unroll
      for (int j = 0; j < 4; ++j)
        bfr[j] = *(const bf16x8*)(bbase[j] + boff + ks * 32);
      __builtin_amdgcn_s_setprio(1);
#pragma unroll
      for (int i = 0; i < 4; ++i)
#pragma unroll
        for (int j = 0; j < 4; ++j)
          acc[i][j] = __builtin_amdgcn_mfma_f32_16x16x32_bf16(af[i], bfr[j], acc[i][j], 0, 0, 0);
      __builtin_amdgcn_s_setprio(0);
    }
    if (it < 15) __syncthreads();  // guard A-buffer reuse (next loads landed during MFMA)
  }

#pragma unroll
  for (int i = 0; i < 4; ++i) {
    int rowb = brow + i * 16 + (lane >> 4) * 4;
#pragma unroll
    for (int j = 0; j < 4; ++j) {
      int col = w * 64 + j * 16 + (lane & 15);
      float b = bias[col];
#pragma unroll
      for (int q = 0; q < 4; ++q) {
        int r = rowb + q;
        if (r < N) C[(size_t)r * DFEAT + col] = acc[i][j][q] + b;
      }
    }
  }
}

// ---------------- launch ----------------

extern "C" void kernel_launch(void* const* d_in, const int* in_sizes, int n_in,
                              void* d_out, int out_size, void* d_ws, size_t ws_size,
                              hipStream_t stream) {
  const float* x = (const float*)d_in[0];
  const int* ei = (const int*)d_in[1];
  const float* weight = (const float*)d_in[2];
  const float* bias = (const float*)d_in[3];
  float* out = (float*)d_out;

  int N = in_sizes[0] / DFEAT;
  int E = in_sizes[1] / 2;
  const int* ei0 = ei;
  const int* ei1 = ei + E;

  char* ws = (char*)d_ws;
  size_t off = 0;
  auto alloc = [&](size_t bytes) {
    void* p = ws + off;
    off = (off + bytes + 255) & ~(size_t)255;
    return p;
  };
  int* cnt = (int*)alloc((size_t)N * sizeof(int));
  float* dis = (float*)alloc((size_t)N * sizeof(float));
  int* colsP = (int*)alloc((size_t)N * RSTRIDE * sizeof(int));
  unsigned short* xbf = (unsigned short*)alloc((size_t)N * DFEAT * 2);
  unsigned short* S1 = (unsigned short*)alloc((size_t)N * DFEAT * 2);
  unsigned short* S2 = (unsigned short*)alloc((size_t)N * DFEAT * 2);
  unsigned short* S3 = (unsigned short*)alloc((size_t)N * DFEAT * 2);
  unsigned short* WT = (unsigned short*)alloc((size_t)4 * DFEAT * DFEAT * 2);

  hipMemsetAsync(cnt, 0, (size_t)N * sizeof(int), stream);

  int eb = (E + 255) / 256;
  int nb = (N + 255) / 256;
  int n4 = N * DFEAT / 4;
  k_build<<<eb, 256, 0, stream>>>(ei0, ei1, E, cnt, colsP);
  k_f2bfwt<<<256 + nb + (n4 + 255) / 256, 256, 0, stream>>>(x, xbf, n4, weight, WT,
                                                            cnt, dis, N, nb);

  // Pure chain: S1 = L x ; S2 = L S1 ; S3 = L S2
  int sgrid = (N + 3) / 4;
  k_spmm_bf<<<sgrid, 256, 0, stream>>>(xbf, S1, cnt, colsP, dis, N);
  k_spmm_bf<<<sgrid, 256, 0, stream>>>(S1, S2, cnt, colsP, dis, N);
  k_spmm_bf<<<sgrid, 256, 0, stream>>>(S2, S3, cnt, colsP, dis, N);

  int ggrid = (N + 63) / 64;
  k_gemm4<<<ggrid, 256, 0, stream>>>(xbf, S1, S2, S3, WT, bias, out, N);
}

// Round 15
// 301.066 us; speedup vs baseline: 1.1020x; 1.1020x over previous
//
#include <hip/hip_runtime.h>
#include <hip/hip_bf16.h>

#define DFEAT 256
#define RSTRIDE 64

typedef __attribute__((ext_vector_type(8))) short bf16x8;
typedef __attribute__((ext_vector_type(4))) float f32x4;

__device__ __forceinline__ float bf2f(unsigned short u) {
  return __builtin_bit_cast(float, ((unsigned)u) << 16);
}
__device__ __forceinline__ unsigned short f2bf(float f) {
  __hip_bfloat16 h = __float2bfloat16(f);  // RTNE
  return *reinterpret_cast<unsigned short*>(&h);
}
__device__ __forceinline__ void gload_lds16(const void* g, void* l) {
  __builtin_amdgcn_global_load_lds(
      (const __attribute__((address_space(1))) void*)g,
      (__attribute__((address_space(3))) void*)l, 16, 0, 0);
}

// ---------------- padded-CSR build: one pass over edges ----------------

__global__ void k_build(const int* __restrict__ ei0, const int* __restrict__ ei1, int E,
                        int* __restrict__ cnt, int* __restrict__ colsP) {
  int i = blockIdx.x * blockDim.x + threadIdx.x;
  if (i >= E) return;
  int r = ei0[i];
  int pos = atomicAdd(&cnt[r], 1);
  if (pos < RSTRIDE) colsP[(size_t)r * RSTRIDE + pos] = ei1[i];
}

// ---------------- fused converts: weight-combine + dis + x->bf16 ----------------
// Blocks [0,256): combined weights, written in MFMA-FRAGMENT ORDER:
//   out = x(W0-W2) + S1(W1-3W3) + S2(2W2) + S3(4W3) + b,  S_k = L^k x
//   WTf element (g, n, k) -> block (g*16 + n/16)*8 + k/32, lane (k/8%4)*16+(n%16),
//   elem k%8. One fragment = 64 lanes x 16B = 1 KB, coalesced wave load.
// Blocks [256,256+nb): dis = rsqrt(deg+1). Blocks [256+nb,...): x f32->bf16.

__global__ __launch_bounds__(256) void k_f2bfwt(const float* __restrict__ x,
                                                unsigned short* __restrict__ xbf, int n4,
                                                const float* __restrict__ W,
                                                unsigned short* __restrict__ WTf,
                                                const int* __restrict__ cnt,
                                                float* __restrict__ dis, int N, int nb) {
  int b = blockIdx.x;
  if (b < 256) {
    int idx = b * 256 + threadIdx.x;  // (k,n) over 65536
    int n = idx & 255;
    int k = idx >> 8;
    float w0 = W[idx];
    float w1 = W[65536 + idx];
    float w2 = W[2 * 65536 + idx];
    float w3 = W[3 * 65536 + idx];
    int jg = n >> 4;
    int lane = ((k >> 3) & 3) * 16 + (n & 15);
    int base = ((jg * 8 + (k >> 5)) << 9) + lane * 8 + (k & 7);
    WTf[base]             = f2bf(w0 - w2);
    WTf[65536 + base]     = f2bf(w1 - 3.0f * w3);
    WTf[2 * 65536 + base] = f2bf(2.0f * w2);
    WTf[3 * 65536 + base] = f2bf(4.0f * w3);
    return;
  }
  if (b < 256 + nb) {
    int i = (b - 256) * 256 + threadIdx.x;
    if (i < N) dis[i] = rsqrtf((float)(cnt[i] + 1));  // deg incl. appended self loop
    return;
  }
  int i = (b - 256 - nb) * 256 + threadIdx.x;
  if (i >= n4) return;
  float4 f = *(const float4*)(x + (size_t)i * 4);
  ushort4 u;
  u.x = f2bf(f.x); u.y = f2bf(f.y); u.z = f2bf(f.z); u.w = f2bf(f.w);
  *(ushort4*)(xbf + (size_t)i * 4) = u;
}

// ---------------- SpMM (bf16): y = L v  (pure Laplacian apply) ----------------
// One wave per row; lane owns 4 contiguous feats. Unroll x4 with early exit
// (4 independent gather chains). No LDS, no shfl, no barrier. R8-validated.

__global__ __launch_bounds__(256) void k_spmm_bf(
    const unsigned short* __restrict__ v, unsigned short* __restrict__ y,
    const int* __restrict__ cnt, const int* __restrict__ colsP,
    const float* __restrict__ dis, int N) {
  int r = blockIdx.x * 4 + (threadIdx.x >> 6);
  if (r >= N) return;
  int lane = threadIdx.x & 63;
  int fo = lane * 4;
  int len = cnt[r];
  if (len > RSTRIDE) len = RSTRIDE;
  const int* cp = colsP + (size_t)r * RSTRIDE;
  float dr = dis[r];
  float a0 = 0.f, a1 = 0.f, a2 = 0.f, a3 = 0.f;

  int e = 0;
  for (; e + 3 < len; e += 4) {
    int c0 = cp[e], c1 = cp[e + 1], c2 = cp[e + 2], c3 = cp[e + 3];
    float l0 = -dr * dis[c0] + (c0 == r ? 1.f : 0.f);
    float l1 = -dr * dis[c1] + (c1 == r ? 1.f : 0.f);
    float l2 = -dr * dis[c2] + (c2 == r ? 1.f : 0.f);
    float l3 = -dr * dis[c3] + (c3 == r ? 1.f : 0.f);
    uint2 u0 = *(const uint2*)(v + (size_t)c0 * DFEAT + fo);
    uint2 u1 = *(const uint2*)(v + (size_t)c1 * DFEAT + fo);
    uint2 u2 = *(const uint2*)(v + (size_t)c2 * DFEAT + fo);
    uint2 u3 = *(const uint2*)(v + (size_t)c3 * DFEAT + fo);
    a0 += l0 * bf2f(u0.x & 0xffff) + l1 * bf2f(u1.x & 0xffff) +
          l2 * bf2f(u2.x & 0xffff) + l3 * bf2f(u3.x & 0xffff);
    a1 += l0 * bf2f(u0.x >> 16) + l1 * bf2f(u1.x >> 16) +
          l2 * bf2f(u2.x >> 16) + l3 * bf2f(u3.x >> 16);
    a2 += l0 * bf2f(u0.y & 0xffff) + l1 * bf2f(u1.y & 0xffff) +
          l2 * bf2f(u2.y & 0xffff) + l3 * bf2f(u3.y & 0xffff);
    a3 += l0 * bf2f(u0.y >> 16) + l1 * bf2f(u1.y >> 16) +
          l2 * bf2f(u2.y >> 16) + l3 * bf2f(u3.y >> 16);
  }
  for (; e < len; ++e) {
    int c = cp[e];
    float lv = -dr * dis[c] + (c == r ? 1.f : 0.f);
    uint2 u = *(const uint2*)(v + (size_t)c * DFEAT + fo);
    a0 += lv * bf2f(u.x & 0xffff);
    a1 += lv * bf2f(u.x >> 16);
    a2 += lv * bf2f(u.y & 0xffff);
    a3 += lv * bf2f(u.y >> 16);
  }

  float sc = 1.0f - dr * dr;  // appended self-loop
  uint2 uv = *(const uint2*)(v + (size_t)r * DFEAT + fo);
  a0 += sc * bf2f(uv.x & 0xffff);
  a1 += sc * bf2f(uv.x >> 16);
  a2 += sc * bf2f(uv.y & 0xffff);
  a3 += sc * bf2f(uv.y >> 16);

  uint2 o;
  o.x = (unsigned)f2bf(a0) | ((unsigned)f2bf(a1) << 16);
  o.y = (unsigned)f2bf(a2) | ((unsigned)f2bf(a3) << 16);
  *(uint2*)(y + (size_t)r * DFEAT + fo) = o;
}

// ---------------- fused MFMA GEMM: out = sum_g Ag @ Wg' + bias ----------------
// BM=64, BN=256 (A read exactly once). 4 waves, 64x64 tile each. BK=64.
// A staged in LDS (8 KB/tile, dbuf = 16 KB; barrier guards only A staging
// issued one iteration early). B fragments loaded from FRAGMENT-ORDERED WTf:
// one fragment = one coalesced 1 KB wave load (lane l <- base + l*16), fixing
// R14's 16-lines-per-instruction TA bottleneck. B never in LDS, no sync.

__global__ __launch_bounds__(256) void k_gemm4(
    const unsigned short* __restrict__ A0, const unsigned short* __restrict__ A1,
    const unsigned short* __restrict__ A2, const unsigned short* __restrict__ A3,
    const unsigned short* __restrict__ WTf,  // fragment-ordered combined weights
    const float* __restrict__ bias, float* __restrict__ C, int N) {
  __shared__ __align__(16) unsigned short As[2][64 * 64];  // 64 rows x 128B
  int tid = threadIdx.x;
  int lane = tid & 63;
  int w = tid >> 6;
  int brow = blockIdx.x * 64;

  f32x4 acc[4][4] = {};

  auto stageA = [&](int buf, int it) {
    int g = it >> 2;
    int k0 = (it & 3) * 64;
    const unsigned short* Asrc = g == 0 ? A0 : g == 1 ? A1 : g == 2 ? A2 : A3;
#pragma unroll
    for (int p = 0; p < 2; ++p) {
      int chunk = p * 256 + w * 64 + lane;  // 0..511 ; dest = base + chunk*16
      int r = chunk >> 3;                   // 0..63
      int s = (chunk & 7) ^ (r & 7);        // pre-swizzled source slot
      int grow = brow + r;
      if (grow >= N) grow = N - 1;
      gload_lds16(Asrc + (size_t)grow * DFEAT + k0 + s * 8,
                  (char*)As[buf] + chunk * 16);
    }
  };

  stageA(0, 0);
  __syncthreads();  // tile 0 ready

  for (int it = 0; it < 16; ++it) {
    int cur = it & 1;
    if (it < 15) stageA(cur ^ 1, it + 1);  // next A-tile flies during compute
    int g = it >> 2;
#pragma unroll
    for (int ksi = 0; ksi < 2; ++ksi) {
      int ks = (it & 3) * 2 + ksi;  // K-step of 32 within this g
      bf16x8 af[4], bfr[4];
#pragma unroll
      for (int i = 0; i < 4; ++i) {
        int row = i * 16 + (lane & 15);
        int slot = (ksi * 4 + (lane >> 4)) ^ (row & 7);
        af[i] = *(const bf16x8*)((const char*)As[cur] + row * 128 + slot * 16);
      }
#pragma unroll
      for (int j = 0; j < 4; ++j)
        bfr[j] = *(const bf16x8*)(WTf + ((((g * 16 + w * 4 + j) * 8) + ks) << 9) +
                                  lane * 8);
      __builtin_amdgcn_s_setprio(1);
#pragma unroll
      for (int i = 0; i < 4; ++i)
#pragma unroll
        for (int j = 0; j < 4; ++j)
          acc[i][j] = __builtin_amdgcn_mfma_f32_16x16x32_bf16(af[i], bfr[j], acc[i][j], 0, 0, 0);
      __builtin_amdgcn_s_setprio(0);
    }
    if (it < 15) __syncthreads();  // guard A-buffer reuse
  }

#pragma unroll
  for (int i = 0; i < 4; ++i) {
    int rowb = brow + i * 16 + (lane >> 4) * 4;
#pragma unroll
    for (int j = 0; j < 4; ++j) {
      int col = w * 64 + j * 16 + (lane & 15);
      float b = bias[col];
#pragma unroll
      for (int q = 0; q < 4; ++q) {
        int r = rowb + q;
        if (r < N) C[(size_t)r * DFEAT + col] = acc[i][j][q] + b;
      }
    }
  }
}

// ---------------- launch ----------------

extern "C" void kernel_launch(void* const* d_in, const int* in_sizes, int n_in,
                              void* d_out, int out_size, void* d_ws, size_t ws_size,
                              hipStream_t stream) {
  const float* x = (const float*)d_in[0];
  const int* ei = (const int*)d_in[1];
  const float* weight = (const float*)d_in[2];
  const float* bias = (const float*)d_in[3];
  float* out = (float*)d_out;

  int N = in_sizes[0] / DFEAT;
  int E = in_sizes[1] / 2;
  const int* ei0 = ei;
  const int* ei1 = ei + E;

  char* ws = (char*)d_ws;
  size_t off = 0;
  auto alloc = [&](size_t bytes) {
    void* p = ws + off;
    off = (off + bytes + 255) & ~(size_t)255;
    return p;
  };
  int* cnt = (int*)alloc((size_t)N * sizeof(int));
  float* dis = (float*)alloc((size_t)N * sizeof(float));
  int* colsP = (int*)alloc((size_t)N * RSTRIDE * sizeof(int));
  unsigned short* xbf = (unsigned short*)alloc((size_t)N * DFEAT * 2);
  unsigned short* S1 = (unsigned short*)alloc((size_t)N * DFEAT * 2);
  unsigned short* S2 = (unsigned short*)alloc((size_t)N * DFEAT * 2);
  unsigned short* S3 = (unsigned short*)alloc((size_t)N * DFEAT * 2);
  unsigned short* WTf = (unsigned short*)alloc((size_t)4 * DFEAT * DFEAT * 2);

  hipMemsetAsync(cnt, 0, (size_t)N * sizeof(int), stream);

  int eb = (E + 255) / 256;
  int nb = (N + 255) / 256;
  int n4 = N * DFEAT / 4;
  k_build<<<eb, 256, 0, stream>>>(ei0, ei1, E, cnt, colsP);
  k_f2bfwt<<<256 + nb + (n4 + 255) / 256, 256, 0, stream>>>(x, xbf, n4, weight, WTf,
                                                            cnt, dis, N, nb);

  // Pure chain: S1 = L x ; S2 = L S1 ; S3 = L S2
  int sgrid = (N + 3) / 4;
  k_spmm_bf<<<sgrid, 256, 0, stream>>>(xbf, S1, cnt, colsP, dis, N);
  k_spmm_bf<<<sgrid, 256, 0, stream>>>(S1, S2, cnt, colsP, dis, N);
  k_spmm_bf<<<sgrid, 256, 0, stream>>>(S2, S3, cnt, colsP, dis, N);

  int ggrid = (N + 63) / 64;
  k_gemm4<<<ggrid, 256, 0, stream>>>(xbf, S1, S2, S3, WTf, bias, out, N);
}

// Round 16
// 300.840 us; speedup vs baseline: 1.1029x; 1.0008x over previous
//
#include <hip/hip_runtime.h>
#include <hip/hip_bf16.h>

#define DFEAT 256
#define RSTRIDE 64

typedef __attribute__((ext_vector_type(8))) short bf16x8;
typedef __attribute__((ext_vector_type(4))) float f32x4;

__device__ __forceinline__ float bf2f(unsigned short u) {
  return __builtin_bit_cast(float, ((unsigned)u) << 16);
}
__device__ __forceinline__ unsigned short f2bf(float f) {
  __hip_bfloat16 h = __float2bfloat16(f);  // RTNE
  return *reinterpret_cast<unsigned short*>(&h);
}
__device__ __forceinline__ void gload_lds16(const void* g, void* l) {
  __builtin_amdgcn_global_load_lds(
      (const __attribute__((address_space(1))) void*)g,
      (__attribute__((address_space(3))) void*)l, 16, 0, 0);
}

// ---------------- padded-CSR build: one pass over edges ----------------

__global__ void k_build(const int* __restrict__ ei0, const int* __restrict__ ei1, int E,
                        int* __restrict__ cnt, int* __restrict__ colsP) {
  int i = blockIdx.x * blockDim.x + threadIdx.x;
  if (i >= E) return;
  int r = ei0[i];
  int pos = atomicAdd(&cnt[r], 1);
  if (pos < RSTRIDE) colsP[(size_t)r * RSTRIDE + pos] = ei1[i];
}

// ---------------- fused converts: weight-combine + dis + x->bf16 ----------------
// Blocks [0,256): combined weights, written in MFMA-FRAGMENT ORDER:
//   out = x(W0-W2) + S1(W1-3W3) + S2(2W2) + S3(4W3) + b,  S_k = L^k x
//   WTf element (g, n, k) -> block (g*16 + n/16)*8 + k/32, lane (k/8%4)*16+(n%16),
//   elem k%8. One fragment = 64 lanes x 16B = 1 KB, coalesced wave load.
// Blocks [256,256+nb): dis = rsqrt(deg+1). Blocks [256+nb,...): x f32->bf16.

__global__ __launch_bounds__(256) void k_f2bfwt(const float* __restrict__ x,
                                                unsigned short* __restrict__ xbf, int n4,
                                                const float* __restrict__ W,
                                                unsigned short* __restrict__ WTf,
                                                const int* __restrict__ cnt,
                                                float* __restrict__ dis, int N, int nb) {
  int b = blockIdx.x;
  if (b < 256) {
    int idx = b * 256 + threadIdx.x;  // (k,n) over 65536
    int n = idx & 255;
    int k = idx >> 8;
    float w0 = W[idx];
    float w1 = W[65536 + idx];
    float w2 = W[2 * 65536 + idx];
    float w3 = W[3 * 65536 + idx];
    int jg = n >> 4;
    int lane = ((k >> 3) & 3) * 16 + (n & 15);
    int base = ((jg * 8 + (k >> 5)) << 9) + lane * 8 + (k & 7);
    WTf[base]             = f2bf(w0 - w2);
    WTf[65536 + base]     = f2bf(w1 - 3.0f * w3);
    WTf[2 * 65536 + base] = f2bf(2.0f * w2);
    WTf[3 * 65536 + base] = f2bf(4.0f * w3);
    return;
  }
  if (b < 256 + nb) {
    int i = (b - 256) * 256 + threadIdx.x;
    if (i < N) dis[i] = rsqrtf((float)(cnt[i] + 1));  // deg incl. appended self loop
    return;
  }
  int i = (b - 256 - nb) * 256 + threadIdx.x;
  if (i >= n4) return;
  float4 f = *(const float4*)(x + (size_t)i * 4);
  ushort4 u;
  u.x = f2bf(f.x); u.y = f2bf(f.y); u.z = f2bf(f.z); u.w = f2bf(f.w);
  *(ushort4*)(xbf + (size_t)i * 4) = u;
}

// ---------------- SpMM (bf16): y = L v  (pure Laplacian apply) ----------------
// One wave per row; lane owns 4 contiguous feats. Unroll x4 with early exit
// (4 independent gather chains). No LDS, no shfl, no barrier. At the random-
// gather memory-system floor (fetch-service ~87% of dur).

__global__ __launch_bounds__(256) void k_spmm_bf(
    const unsigned short* __restrict__ v, unsigned short* __restrict__ y,
    const int* __restrict__ cnt, const int* __restrict__ colsP,
    const float* __restrict__ dis, int N) {
  int r = blockIdx.x * 4 + (threadIdx.x >> 6);
  if (r >= N) return;
  int lane = threadIdx.x & 63;
  int fo = lane * 4;
  int len = cnt[r];
  if (len > RSTRIDE) len = RSTRIDE;
  const int* cp = colsP + (size_t)r * RSTRIDE;
  float dr = dis[r];
  float a0 = 0.f, a1 = 0.f, a2 = 0.f, a3 = 0.f;

  int e = 0;
  for (; e + 3 < len; e += 4) {
    int c0 = cp[e], c1 = cp[e + 1], c2 = cp[e + 2], c3 = cp[e + 3];
    float l0 = -dr * dis[c0] + (c0 == r ? 1.f : 0.f);
    float l1 = -dr * dis[c1] + (c1 == r ? 1.f : 0.f);
    float l2 = -dr * dis[c2] + (c2 == r ? 1.f : 0.f);
    float l3 = -dr * dis[c3] + (c3 == r ? 1.f : 0.f);
    uint2 u0 = *(const uint2*)(v + (size_t)c0 * DFEAT + fo);
    uint2 u1 = *(const uint2*)(v + (size_t)c1 * DFEAT + fo);
    uint2 u2 = *(const uint2*)(v + (size_t)c2 * DFEAT + fo);
    uint2 u3 = *(const uint2*)(v + (size_t)c3 * DFEAT + fo);
    a0 += l0 * bf2f(u0.x & 0xffff) + l1 * bf2f(u1.x & 0xffff) +
          l2 * bf2f(u2.x & 0xffff) + l3 * bf2f(u3.x & 0xffff);
    a1 += l0 * bf2f(u0.x >> 16) + l1 * bf2f(u1.x >> 16) +
          l2 * bf2f(u2.x >> 16) + l3 * bf2f(u3.x >> 16);
    a2 += l0 * bf2f(u0.y & 0xffff) + l1 * bf2f(u1.y & 0xffff) +
          l2 * bf2f(u2.y & 0xffff) + l3 * bf2f(u3.y & 0xffff);
    a3 += l0 * bf2f(u0.y >> 16) + l1 * bf2f(u1.y >> 16) +
          l2 * bf2f(u2.y >> 16) + l3 * bf2f(u3.y >> 16);
  }
  for (; e < len; ++e) {
    int c = cp[e];
    float lv = -dr * dis[c] + (c == r ? 1.f : 0.f);
    uint2 u = *(const uint2*)(v + (size_t)c * DFEAT + fo);
    a0 += lv * bf2f(u.x & 0xffff);
    a1 += lv * bf2f(u.x >> 16);
    a2 += lv * bf2f(u.y & 0xffff);
    a3 += lv * bf2f(u.y >> 16);
  }

  float sc = 1.0f - dr * dr;  // appended self-loop
  uint2 uv = *(const uint2*)(v + (size_t)r * DFEAT + fo);
  a0 += sc * bf2f(uv.x & 0xffff);
  a1 += sc * bf2f(uv.x >> 16);
  a2 += sc * bf2f(uv.y & 0xffff);
  a3 += sc * bf2f(uv.y >> 16);

  uint2 o;
  o.x = (unsigned)f2bf(a0) | ((unsigned)f2bf(a1) << 16);
  o.y = (unsigned)f2bf(a2) | ((unsigned)f2bf(a3) << 16);
  *(uint2*)(y + (size_t)r * DFEAT + fo) = o;
}

// ---------------- fused MFMA GEMM: out = sum_g Ag @ Wg' + bias ----------------
// BM=64, BN=256 (A read exactly once). 4 waves, 64x64 tile each. BK=64.
// A: THREE 8 KB LDS buffers, stage(it+2) issued at END of iter (after B
// loads, so B-use drains only old loads); top-of-loop s_waitcnt vmcnt(2) +
// bare s_barrier certifies 1-iter-old stage loads while the newest 2 stay in
// flight. NO vmcnt(0) in the loop (T4). B: fragment-ordered WTf, one
// coalesced 1 KB wave load per fragment, never in LDS, no sync.

__global__ __launch_bounds__(256) void k_gemm4(
    const unsigned short* __restrict__ A0, const unsigned short* __restrict__ A1,
    const unsigned short* __restrict__ A2, const unsigned short* __restrict__ A3,
    const unsigned short* __restrict__ WTf,  // fragment-ordered combined weights
    const float* __restrict__ bias, float* __restrict__ C, int N) {
  __shared__ __align__(16) unsigned short As[3][64 * 64];  // 3 x 8 KB
  int tid = threadIdx.x;
  int lane = tid & 63;
  int w = tid >> 6;
  int brow = blockIdx.x * 64;

  f32x4 acc[4][4] = {};

  auto stageA = [&](int buf, int it) {
    int g = it >> 2;
    int k0 = (it & 3) * 64;
    const unsigned short* Asrc = g == 0 ? A0 : g == 1 ? A1 : g == 2 ? A2 : A3;
#pragma unroll
    for (int p = 0; p < 2; ++p) {
      int chunk = p * 256 + w * 64 + lane;  // 0..511 ; dest = base + chunk*16
      int r = chunk >> 3;                   // 0..63
      int s = (chunk & 7) ^ (r & 7);        // pre-swizzled source slot
      int grow = brow + r;
      if (grow >= N) grow = N - 1;
      gload_lds16(Asrc + (size_t)grow * DFEAT + k0 + s * 8,
                  (char*)As[buf] + chunk * 16);
    }
  };

  stageA(0, 0);
  stageA(1, 1);

  for (int it = 0; it < 16; ++it) {
    // Certify stage(it): with stage(it+1) the only newer loads (B retired by
    // consumption), vmcnt(2) guarantees this iter's A-tile landed; barrier
    // publishes all waves' stores. Loads for it+1 stay in flight.
    asm volatile("s_waitcnt vmcnt(2)\n\ts_barrier" ::: "memory");
    __builtin_amdgcn_sched_barrier(0);
    int cur = it % 3;
    int g = it >> 2;
#pragma unroll
    for (int ksi = 0; ksi < 2; ++ksi) {
      int ks = (it & 3) * 2 + ksi;  // K-step of 32 within this g
      bf16x8 af[4], bfr[4];
#pragma unroll
      for (int i = 0; i < 4; ++i) {
        int row = i * 16 + (lane & 15);
        int slot = (ksi * 4 + (lane >> 4)) ^ (row & 7);
        af[i] = *(const bf16x8*)((const char*)As[cur] + row * 128 + slot * 16);
      }
#pragma unroll
      for (int j = 0; j < 4; ++j)
        bfr[j] = *(const bf16x8*)(WTf + ((((g * 16 + w * 4 + j) * 8) + ks) << 9) +
                                  lane * 8);
      __builtin_amdgcn_s_setprio(1);
#pragma unroll
      for (int i = 0; i < 4; ++i)
#pragma unroll
        for (int j = 0; j < 4; ++j)
          acc[i][j] = __builtin_amdgcn_mfma_f32_16x16x32_bf16(af[i], bfr[j], acc[i][j], 0, 0, 0);
      __builtin_amdgcn_s_setprio(0);
    }
    // Refill buf[(it+2)%3] == buf[(it-1)%3]: every wave's reads of that
    // buffer retired before it crossed THIS iter's top barrier -> safe.
    // Issued after B loads so B-consumption waits never certify these.
    if (it < 14) stageA((it + 2) % 3, it + 2);
  }

#pragma unroll
  for (int i = 0; i < 4; ++i) {
    int rowb = brow + i * 16 + (lane >> 4) * 4;
#pragma unroll
    for (int j = 0; j < 4; ++j) {
      int col = w * 64 + j * 16 + (lane & 15);
      float b = bias[col];
#pragma unroll
      for (int q = 0; q < 4; ++q) {
        int r = rowb + q;
        if (r < N) C[(size_t)r * DFEAT + col] = acc[i][j][q] + b;
      }
    }
  }
}

// ---------------- launch ----------------

extern "C" void kernel_launch(void* const* d_in, const int* in_sizes, int n_in,
                              void* d_out, int out_size, void* d_ws, size_t ws_size,
                              hipStream_t stream) {
  const float* x = (const float*)d_in[0];
  const int* ei = (const int*)d_in[1];
  const float* weight = (const float*)d_in[2];
  const float* bias = (const float*)d_in[3];
  float* out = (float*)d_out;

  int N = in_sizes[0] / DFEAT;
  int E = in_sizes[1] / 2;
  const int* ei0 = ei;
  const int* ei1 = ei + E;

  char* ws = (char*)d_ws;
  size_t off = 0;
  auto alloc = [&](size_t bytes) {
    void* p = ws + off;
    off = (off + bytes + 255) & ~(size_t)255;
    return p;
  };
  int* cnt = (int*)alloc((size_t)N * sizeof(int));
  float* dis = (float*)alloc((size_t)N * sizeof(float));
  int* colsP = (int*)alloc((size_t)N * RSTRIDE * sizeof(int));
  unsigned short* xbf = (unsigned short*)alloc((size_t)N * DFEAT * 2);
  unsigned short* S1 = (unsigned short*)alloc((size_t)N * DFEAT * 2);
  unsigned short* S2 = (unsigned short*)alloc((size_t)N * DFEAT * 2);
  unsigned short* S3 = (unsigned short*)alloc((size_t)N * DFEAT * 2);
  unsigned short* WTf = (unsigned short*)alloc((size_t)4 * DFEAT * DFEAT * 2);

  hipMemsetAsync(cnt, 0, (size_t)N * sizeof(int), stream);

  int eb = (E + 255) / 256;
  int nb = (N + 255) / 256;
  int n4 = N * DFEAT / 4;
  k_build<<<eb, 256, 0, stream>>>(ei0, ei1, E, cnt, colsP);
  k_f2bfwt<<<256 + nb + (n4 + 255) / 256, 256, 0, stream>>>(x, xbf, n4, weight, WTf,
                                                            cnt, dis, N, nb);

  // Pure chain: S1 = L x ; S2 = L S1 ; S3 = L S2
  int sgrid = (N + 3) / 4;
  k_spmm_bf<<<sgrid, 256, 0, stream>>>(xbf, S1, cnt, colsP, dis, N);
  k_spmm_bf<<<sgrid, 256, 0, stream>>>(S1, S2, cnt, colsP, dis, N);
  k_spmm_bf<<<sgrid, 256, 0, stream>>>(S2, S3, cnt, colsP, dis, N);

  int ggrid = (N + 63) / 64;
  k_gemm4<<<ggrid, 256, 0, stream>>>(xbf, S1, S2, S3, WTf, bias, out, N);
}